// Round 8
// baseline (238.137 us; speedup 1.0000x reference)
//
#include <hip/hip_runtime.h>

// GaussianPooling: fm[512,256,256] f32, keypoints[4096,2] int, out[4096,512] f32.
// 5x5 gaussian sigma=2, separable: k = g(dy)*g(dx)/s^2.
//
// R8: R7 counters showed the real killer: scattered out[n][c] dword stores ->
// WRITE_SIZE 86 MB for 8.4 MB of data (each 64B line partially written by 16
// channel-blocks on different XCDs -> per-sector flushes), plus 7.4M LDS bank
// conflict cycles from an unpadded ring. Fix: R6 pool structure (c,q blocks,
// padded 36x260 LDS slice, 4 blocks/CU) storing slot-compacted
// outT[c][q*4096+slot] (coalesced, single-writer full lines), then a
// slot-driven transpose: read dense slot runs coalesced, write out[n][c-tile]
// as full 256B segments (one writer per line). Bucket = R6 one-shot atomic.

#define NC  512
#define NH  256
#define NW  256
#define NKP 4096

#define OCT 8
#define SLICE_ROWS 36          // 32 + 2x2 halo
#define STR 260                // LDS row stride: +4 keeps 16B align, rotates banks
#define OTS (OCT * NKP)        // outT row stride in floats (32768)

// ws layout:
//   ints [0..8)                 cnt[8]  (zeroed by hipMemsetAsync)
//   ints [8192 .. 8192+8*NKP)   packed lists (i | x<<12 | y<<20), stride NKP
//   byte 1<<20 ..               outT [NC][OTS] floats (64 MB)
#define WS_LIST_OFF_I 8192
#define WS_OUTT_OFF_B (1 << 20)

// ---------------- bucket: 1 kp/thread, LDS hist + global range reservation ----------------
__global__ __launch_bounds__(256) void bucket_kernel(
    const int* __restrict__ kp, unsigned* __restrict__ ws_i, int n_kp)
{
    __shared__ int hist[OCT];
    __shared__ int base[OCT];
    const int t = threadIdx.x;
    const int i = blockIdx.x * 256 + t;

    if (t < OCT) hist[t] = 0;
    __syncthreads();

    int q = 0, lr = 0;
    unsigned pk = 0;
    const bool valid = (i < n_kp);
    if (valid) {
        int x = kp[2 * i + 0];
        int y = kp[2 * i + 1];
        x = min(max(x, 2), NW - 3);
        y = min(max(y, 2), NH - 3);
        q  = y >> 5;
        lr = atomicAdd(&hist[q], 1);
        pk = (unsigned)i | ((unsigned)x << 12) | ((unsigned)y << 20);
    }
    __syncthreads();

    if (t < OCT) base[t] = atomicAdd((int*)&ws_i[t], hist[t]);
    __syncthreads();

    if (valid)
        ws_i[WS_LIST_OFF_I + q * NKP + base[q] + lr] = pk;
}

// ---------------- pool: block = (channel, y-octant), plane slice in LDS ----------------
__global__ __launch_bounds__(512) void pool_kernel(
    const float* __restrict__ fm, const unsigned* __restrict__ ws_i,
    float* __restrict__ outT)
{
    __shared__ float plane[SLICE_ROWS * STR];   // 37,440 B -> 4 blocks/CU

    const int c = blockIdx.x;
    const int q = blockIdx.y;
    const int t = threadIdx.x;
    const int ybase = q * 32 - 2;

    // stage rows [ybase, ybase+35] clamped to [0,255]; fully coalesced float4
    const float4* src = (const float4*)(fm + ((size_t)c << 16));
#pragma unroll
    for (int it = 0; it < 5; ++it) {
        const int i = t + it * 512;
        if (i < SLICE_ROWS * 64) {
            const int row  = i >> 6;
            const int col4 = i & 63;
            const int gr   = ybase + row;
            if ((unsigned)gr < 256u) {
                float4 v = src[(gr << 6) + col4];
                *(float4*)&plane[row * STR + (col4 << 2)] = v;
            }
        }
    }
    __syncthreads();

    // gaussian weights
    const float e1 = 0.8824969025845955f;  // exp(-1/8)
    const float e2 = 0.6065306597126334f;  // exp(-4/8)
    const float s  = 2.0f * (e1 + e2) + 1.0f;
    const float inv_s2 = 1.0f / (s * s);
    const float g[5] = {e2, e1, 1.0f, e1, e2};
    float gy[5];
#pragma unroll
    for (int i = 0; i < 5; i++) gy[i] = g[i] * inv_s2;

    const int cnt = (int)ws_i[q];
    const unsigned* list = ws_i + WS_LIST_OFF_I + q * NKP;
    float* orow = outT + (size_t)c * OTS + q * NKP;

    for (int e = t; e < cnt; e += 512) {
        const unsigned pk = list[e];
        const int xc = (int)((pk >> 12) & 0xFFu);
        const int yc = (int)((pk >> 20) & 0xFFu);

        const int x0 = xc - 2;
        const int r  = x0 & 3;
        const int xa = x0 - r;
        float wx[8];
#pragma unroll
        for (int i = 0; i < 8; i++)
            wx[i] = (i >= r && i < r + 5) ? g[i - r] : 0.0f;

        const int lr0 = yc - (q << 5);   // plane row of (yc-2): 0..31
        float acc = 0.0f;
#pragma unroll
        for (int dy = 0; dy < 5; dy++) {
            const float* rowp = &plane[(lr0 + dy) * STR + xa];
            float4 a = *(const float4*)rowp;
            float4 b = *(const float4*)(rowp + 4);
            acc += gy[dy] * (a.x * wx[0] + a.y * wx[1] + a.z * wx[2] + a.w * wx[3]
                           + b.x * wx[4] + b.y * wx[5] + b.z * wx[6] + b.w * wx[7]);
        }
        orow[e] = acc;   // coalesced, block-owned slot range: full-line single writer
    }
}

// ---------------- final: slot-driven transpose outT -> out[n][c] ----------------
// block = (ctile of 64, octant q); reads 64-slot x 64-c tiles coalesced,
// writes out[n][c0..c0+63] contiguous (full 64B lines, one writer each).
__global__ __launch_bounds__(256) void outt_kernel(
    const float* __restrict__ outT, const unsigned* __restrict__ ws_i,
    float* __restrict__ out)
{
    __shared__ float tile[64][65];
    __shared__ int n_s[64];
    const int c0 = blockIdx.x * 64;
    const int q  = blockIdx.y;
    const int tx = threadIdx.x;   // 0..63
    const int ty = threadIdx.y;   // 0..3

    const int cnt = (int)ws_i[q];
    const unsigned* list = ws_i + WS_LIST_OFF_I + q * NKP;

    for (int s0 = 0; s0 < cnt; s0 += 64) {
        const int nrem = min(64, cnt - s0);

        if (ty == 0)
            n_s[tx] = (tx < nrem) ? (int)(list[s0 + tx] & 0xFFFu) : 0;

        // load: lane tx = slot, row = channel; coalesced along slots
#pragma unroll
        for (int k = 0; k < 64; k += 4) {
            const int cc = k + ty;
            tile[tx][cc] = (tx < nrem)
                ? outT[(size_t)(c0 + cc) * OTS + q * NKP + s0 + tx] : 0.0f;
        }
        __syncthreads();

        // store: lane tx = channel, row = slot; 256B contiguous per slot
#pragma unroll
        for (int k = 0; k < 64; k += 4) {
            const int i = k + ty;
            if (i < nrem)
                out[(size_t)n_s[i] * NC + c0 + tx] = tile[i][tx];
        }
        __syncthreads();
    }
}

// ---------------- fallback (round-1 direct kernel) ----------------
__global__ __launch_bounds__(256) void gpool_direct_kernel(
    const float* __restrict__ fm, const int* __restrict__ kp,
    float* __restrict__ out)
{
    const int n = blockIdx.x;
    const int t = threadIdx.x;

    int x = kp[2 * n + 0];
    int y = kp[2 * n + 1];
    x = min(max(x, 2), NW - 3);
    y = min(max(y, 2), NH - 3);

    const float e1 = 0.8824969025845955f;
    const float e2 = 0.6065306597126334f;
    const float s  = 2.0f * (e1 + e2) + 1.0f;
    const float inv_s2 = 1.0f / (s * s);
    float g[5] = {e2, e1, 1.0f, e1, e2};
    float gy[5];
#pragma unroll
    for (int i = 0; i < 5; i++) gy[i] = g[i] * inv_s2;

    const int x0 = x - 2;
    const int r  = x0 & 3;
    const int xa = x0 - r;
    float wx[8];
#pragma unroll
    for (int i = 0; i < 8; i++)
        wx[i] = (i >= r && i < r + 5) ? g[i - r] : 0.0f;

    const float* base0 = fm + ((size_t)t * NH + (y - 2)) * NW + xa;
    const float* base1 = fm + ((size_t)(t + 256) * NH + (y - 2)) * NW + xa;

    float acc0 = 0.0f, acc1 = 0.0f;
#pragma unroll
    for (int dy = 0; dy < 5; dy++) {
        const float4* p0 = (const float4*)(base0 + dy * NW);
        const float4* p1 = (const float4*)(base1 + dy * NW);
        float4 a0 = p0[0], b0 = p0[1], a1 = p1[0], b1 = p1[1];
        acc0 += gy[dy] * (a0.x * wx[0] + a0.y * wx[1] + a0.z * wx[2] + a0.w * wx[3]
                        + b0.x * wx[4] + b0.y * wx[5] + b0.z * wx[6] + b0.w * wx[7]);
        acc1 += gy[dy] * (a1.x * wx[0] + a1.y * wx[1] + a1.z * wx[2] + a1.w * wx[3]
                        + b1.x * wx[4] + b1.y * wx[5] + b1.z * wx[6] + b1.w * wx[7]);
    }

    out[(size_t)n * NC + t]       = acc0;
    out[(size_t)n * NC + t + 256] = acc1;
}

extern "C" void kernel_launch(void* const* d_in, const int* in_sizes, int n_in,
                              void* d_out, int out_size, void* d_ws, size_t ws_size,
                              hipStream_t stream)
{
    const float* fm  = (const float*)d_in[0];
    const int*   kp  = (const int*)d_in[1];
    float*       out = (float*)d_out;
    const int n_kp   = in_sizes[1] / 2;   // 4096

    const size_t need = WS_OUTT_OFF_B + (size_t)NC * OTS * sizeof(float);
    if (ws_size >= need && n_kp == NKP) {
        unsigned* ws_i = (unsigned*)d_ws;
        float* outT    = (float*)((char*)d_ws + WS_OUTT_OFF_B);

        hipMemsetAsync(d_ws, 0, OCT * sizeof(unsigned), stream);   // zero cnt[8]

        bucket_kernel<<<(NKP + 255) / 256, 256, 0, stream>>>(kp, ws_i, n_kp);

        dim3 pgrid(NC, OCT);
        pool_kernel<<<pgrid, 512, 0, stream>>>(fm, ws_i, outT);

        dim3 ogrid(NC / 64, OCT);
        dim3 oblk(64, 4);
        outt_kernel<<<ogrid, oblk, 0, stream>>>(outT, ws_i, out);
    } else {
        gpool_direct_kernel<<<n_kp, 256, 0, stream>>>(fm, kp, out);
    }
}

// Round 9
// 203.372 us; speedup vs baseline: 1.1709x; 1.1709x over previous
//
#include <hip/hip_runtime.h>

// GaussianPooling: fm[512,256,256] f32, keypoints[4096,2] int, out[4096,512] f32.
// 5x5 gaussian sigma=2, separable: k = g(dy)*g(dx)/s^2.
//
// R9 (= R6 structure + two fixes, no extra pass):
//  - XCD write-merge swizzle: out-line (n, c0..c0+15) is written by the 16
//    blocks (c0..c0+15, q(n)). Map flat blockIdx b = (chunk&7) + 8*inner
//    (chunk=c>>4) so those 16 blocks share b%8 -> same XCD -> their dword
//    stores merge in that XCD's L2 into full 64B lines (R7 measured 86 MB
//    writeback for 8.4 MB of data without this).
//  - 16-row strips (20x260 LDS = 20.8 KB -> 7 blocks/CU, 28 waves/CU, 8192
//    blocks): denser interleave of staging phases keeps loads in flight
//    through barriers (R6's 36KB/4-block cohorts ran reads at ~2.1 TB/s).

#define NC  512
#define NH  256
#define NW  256
#define NKP 4096

#define NSTRIP 16              // y-strips of 16 rows
#define SLICE_ROWS 20          // 16 + 2x2 halo
#define STR 260                // LDS row stride: +4 keeps 16B align, rotates banks

// ws layout (int32 offsets):
//   [0..16)                    cnt[16]  (zeroed by hipMemsetAsync)
//   [8192 .. 8192+16*NKP)      packed lists (i | x<<12 | y<<20), stride NKP
#define WS_LIST_OFF_I 8192

// ---------------- bucket: 1 kp/thread, LDS hist + global range reservation ----------------
__global__ __launch_bounds__(256) void bucket_kernel(
    const int* __restrict__ kp, unsigned* __restrict__ ws_i, int n_kp)
{
    __shared__ int hist[NSTRIP];
    __shared__ int base[NSTRIP];
    const int t = threadIdx.x;
    const int i = blockIdx.x * 256 + t;

    if (t < NSTRIP) hist[t] = 0;
    __syncthreads();

    int q = 0, lr = 0;
    unsigned pk = 0;
    const bool valid = (i < n_kp);
    if (valid) {
        int x = kp[2 * i + 0];
        int y = kp[2 * i + 1];
        x = min(max(x, 2), NW - 3);
        y = min(max(y, 2), NH - 3);
        q  = y >> 4;
        lr = atomicAdd(&hist[q], 1);
        pk = (unsigned)i | ((unsigned)x << 12) | ((unsigned)y << 20);
    }
    __syncthreads();

    if (t < NSTRIP) base[t] = atomicAdd((int*)&ws_i[t], hist[t]);
    __syncthreads();

    if (valid)
        ws_i[WS_LIST_OFF_I + q * NKP + base[q] + lr] = pk;
}

// ---------------- pool: 1-D grid of 8192, decode (c,q) with XCD swizzle ----------------
__global__ __launch_bounds__(256) void pool_kernel(
    const float* __restrict__ fm, const unsigned* __restrict__ ws_i,
    float* __restrict__ out)
{
    __shared__ float plane[SLICE_ROWS * STR];   // 20,800 B -> 7 blocks/CU

    // decode swizzled block id: b = (chunk&7) + 8*((chunk>>3)*256 + q*16 + lane)
    const int b     = blockIdx.x;
    const int x7    = b & 7;
    const int inner = b >> 3;
    const int hi    = inner >> 8;          // chunk>>3, 0..3
    const int rem   = inner & 255;
    const int q     = rem >> 4;            // 0..15
    const int lane  = rem & 15;
    const int chunk = (hi << 3) | x7;      // 0..31
    const int c     = (chunk << 4) | lane; // 0..511

    const int t = threadIdx.x;
    const int ybase = (q << 4) - 2;

    // stage rows [ybase, ybase+19] clamped to [0,255]; fully coalesced float4
    const float4* src = (const float4*)(fm + ((size_t)c << 16));
#pragma unroll
    for (int it = 0; it < 5; ++it) {
        const int i = t + it * 256;        // 0..1279 = 20 rows * 64 float4
        const int row  = i >> 6;
        const int col4 = i & 63;
        const int gr   = ybase + row;
        if ((unsigned)gr < 256u) {
            float4 v = src[(gr << 6) + col4];
            *(float4*)&plane[row * STR + (col4 << 2)] = v;
        }
    }
    __syncthreads();

    // gaussian weights
    const float e1 = 0.8824969025845955f;  // exp(-1/8)
    const float e2 = 0.6065306597126334f;  // exp(-4/8)
    const float s  = 2.0f * (e1 + e2) + 1.0f;
    const float inv_s2 = 1.0f / (s * s);
    const float g[5] = {e2, e1, 1.0f, e1, e2};
    float gy[5];
#pragma unroll
    for (int i = 0; i < 5; i++) gy[i] = g[i] * inv_s2;

    const int cnt = (int)ws_i[q];
    const unsigned* list = ws_i + WS_LIST_OFF_I + q * NKP;

    for (int e = t; e < cnt; e += 256) {
        const unsigned pk = list[e];
        const int n  = (int)(pk & 0xFFFu);
        const int xc = (int)((pk >> 12) & 0xFFu);
        const int yc = (int)((pk >> 20) & 0xFFu);

        const int x0 = xc - 2;
        const int r  = x0 & 3;
        const int xa = x0 - r;
        float wx[8];
#pragma unroll
        for (int i = 0; i < 8; i++)
            wx[i] = (i >= r && i < r + 5) ? g[i - r] : 0.0f;

        const int lr0 = yc - (q << 4);     // plane row of (yc-2): 0..15
        float acc = 0.0f;
#pragma unroll
        for (int dy = 0; dy < 5; dy++) {
            const float* rowp = &plane[(lr0 + dy) * STR + xa];
            float4 a = *(const float4*)rowp;
            float4 b4 = *(const float4*)(rowp + 4);
            acc += gy[dy] * (a.x * wx[0] + a.y * wx[1] + a.z * wx[2] + a.w * wx[3]
                           + b4.x * wx[4] + b4.y * wx[5] + b4.z * wx[6] + b4.w * wx[7]);
        }
        out[(size_t)n * NC + c] = acc;     // dword store; merges in same-XCD L2
    }
}

// ---------------- fallback (round-1 direct kernel) ----------------
__global__ __launch_bounds__(256) void gpool_direct_kernel(
    const float* __restrict__ fm, const int* __restrict__ kp,
    float* __restrict__ out)
{
    const int n = blockIdx.x;
    const int t = threadIdx.x;

    int x = kp[2 * n + 0];
    int y = kp[2 * n + 1];
    x = min(max(x, 2), NW - 3);
    y = min(max(y, 2), NH - 3);

    const float e1 = 0.8824969025845955f;
    const float e2 = 0.6065306597126334f;
    const float s  = 2.0f * (e1 + e2) + 1.0f;
    const float inv_s2 = 1.0f / (s * s);
    float g[5] = {e2, e1, 1.0f, e1, e2};
    float gy[5];
#pragma unroll
    for (int i = 0; i < 5; i++) gy[i] = g[i] * inv_s2;

    const int x0 = x - 2;
    const int r  = x0 & 3;
    const int xa = x0 - r;
    float wx[8];
#pragma unroll
    for (int i = 0; i < 8; i++)
        wx[i] = (i >= r && i < r + 5) ? g[i - r] : 0.0f;

    const float* base0 = fm + ((size_t)t * NH + (y - 2)) * NW + xa;
    const float* base1 = fm + ((size_t)(t + 256) * NH + (y - 2)) * NW + xa;

    float acc0 = 0.0f, acc1 = 0.0f;
#pragma unroll
    for (int dy = 0; dy < 5; dy++) {
        const float4* p0 = (const float4*)(base0 + dy * NW);
        const float4* p1 = (const float4*)(base1 + dy * NW);
        float4 a0 = p0[0], b0 = p0[1], a1 = p1[0], b1 = p1[1];
        acc0 += gy[dy] * (a0.x * wx[0] + a0.y * wx[1] + a0.z * wx[2] + a0.w * wx[3]
                        + b0.x * wx[4] + b0.y * wx[5] + b0.z * wx[6] + b0.w * wx[7]);
        acc1 += gy[dy] * (a1.x * wx[0] + a1.y * wx[1] + a1.z * wx[2] + a1.w * wx[3]
                        + b1.x * wx[4] + b1.y * wx[5] + b1.z * wx[6] + b1.w * wx[7]);
    }

    out[(size_t)n * NC + t]       = acc0;
    out[(size_t)n * NC + t + 256] = acc1;
}

extern "C" void kernel_launch(void* const* d_in, const int* in_sizes, int n_in,
                              void* d_out, int out_size, void* d_ws, size_t ws_size,
                              hipStream_t stream)
{
    const float* fm  = (const float*)d_in[0];
    const int*   kp  = (const int*)d_in[1];
    float*       out = (float*)d_out;
    const int n_kp   = in_sizes[1] / 2;   // 4096

    const size_t need = (WS_LIST_OFF_I + (size_t)NSTRIP * NKP) * sizeof(unsigned);
    if (ws_size >= need && n_kp == NKP) {
        unsigned* ws_i = (unsigned*)d_ws;

        hipMemsetAsync(d_ws, 0, NSTRIP * sizeof(unsigned), stream);   // zero cnt[16]

        bucket_kernel<<<(NKP + 255) / 256, 256, 0, stream>>>(kp, ws_i, n_kp);

        pool_kernel<<<NC * NSTRIP, 256, 0, stream>>>(fm, ws_i, out);
    } else {
        gpool_direct_kernel<<<n_kp, 256, 0, stream>>>(fm, kp, out);
    }
}